// Round 13
// baseline (447.396 us; speedup 1.0000x reference)
//
#include <hip/hip_runtime.h>
#include <hip/hip_bf16.h>

#define T_ 4
#define FI_ 128
#define FO_ 64
#define KD 512     // T*FI
#define OD 256     // T*FO

#define RBIN 65536 // u8-packed LDS histogram bins per partition (64 KB)
#define RBW (RBIN/4)
#define BCH 128    // edge chunks (= rank-partial rows)

typedef __attribute__((ext_vector_type(8))) short bf16x8;
typedef __attribute__((ext_vector_type(4))) float f32x4;

static __device__ __forceinline__ float bf2f(unsigned short u){
  return __uint_as_float(((unsigned int)u) << 16);
}
static __device__ __forceinline__ unsigned short f2bf(float f){
  unsigned int u = __float_as_uint(f);
  u += 0x7FFFu + ((u >> 16) & 1u);
  return (unsigned short)(u >> 16);
}
// async global->LDS, 16B per lane; LDS dest = uniform base + lane*16 (linear)
static __device__ __forceinline__ void glds16(const void* g, void* l){
  __builtin_amdgcn_global_load_lds(
    (const __attribute__((address_space(1))) unsigned int*)g,
    (__attribute__((address_space(3))) unsigned int*)l, 16, 0, 0);
}

// ---- outdeg histogram: u8-packed LDS bins (4/word), node-partitioned ----
__global__ __launch_bounds__(256) void k_hist_out(const int* __restrict__ src,
    unsigned char* __restrict__ cnt_out, int e, int n, int C)
{
  __shared__ unsigned h[RBW];
  for (int j = threadIdx.x; j < RBW; j += 256) h[j] = 0;
  __syncthreads();
  const int lo  = blockIdx.y * RBIN;
  const int beg = blockIdx.x * C;
  const int end = min(beg + C, e);
  for (int i = beg + (int)threadIdx.x*4; i < end; i += 1024){
    if (i + 3 < end){
      int4 s4 = *(const int4*)(src + i);
      unsigned x0 = (unsigned)(s4.x - lo), x1 = (unsigned)(s4.y - lo);
      unsigned x2 = (unsigned)(s4.z - lo), x3 = (unsigned)(s4.w - lo);
      if (x0 < RBIN) atomicAdd(&h[x0>>2], 1u << ((x0&3)*8));
      if (x1 < RBIN) atomicAdd(&h[x1>>2], 1u << ((x1&3)*8));
      if (x2 < RBIN) atomicAdd(&h[x2>>2], 1u << ((x2&3)*8));
      if (x3 < RBIN) atomicAdd(&h[x3>>2], 1u << ((x3&3)*8));
    } else {
      for (int k = i; k < end; k++){
        unsigned x = (unsigned)(src[k] - lo);
        if (x < RBIN) atomicAdd(&h[x>>2], 1u << ((x&3)*8));
      }
    }
  }
  __syncthreads();
  const int hi = min(RBIN, n - lo);
  unsigned* row = (unsigned*)(cnt_out + (size_t)blockIdx.x * n + lo);
  for (int j = threadIdx.x; j*4 < hi; j += 256) row[j] = h[j];
}

// ---- indeg histogram + per-edge u8 rank (packed LDS fetch_add) ----
__global__ __launch_bounds__(256) void k_hist_in(const int* __restrict__ dst,
    unsigned char* __restrict__ cnt_in, unsigned char* __restrict__ epos,
    int e, int n, int C)
{
  __shared__ unsigned h[RBW];
  for (int j = threadIdx.x; j < RBW; j += 256) h[j] = 0;
  __syncthreads();
  const int lo  = blockIdx.y * RBIN;
  const int beg = blockIdx.x * C;
  const int end = min(beg + C, e);
  for (int i = beg + (int)threadIdx.x*4; i < end; i += 1024){
    if (i + 3 < end){
      int4 d4 = *(const int4*)(dst + i);
      unsigned x0 = (unsigned)(d4.x - lo), x1 = (unsigned)(d4.y - lo);
      unsigned x2 = (unsigned)(d4.z - lo), x3 = (unsigned)(d4.w - lo);
      if (x0 < RBIN){ unsigned o = atomicAdd(&h[x0>>2], 1u << ((x0&3)*8));
                      epos[i  ] = (unsigned char)(o >> ((x0&3)*8)); }
      if (x1 < RBIN){ unsigned o = atomicAdd(&h[x1>>2], 1u << ((x1&3)*8));
                      epos[i+1] = (unsigned char)(o >> ((x1&3)*8)); }
      if (x2 < RBIN){ unsigned o = atomicAdd(&h[x2>>2], 1u << ((x2&3)*8));
                      epos[i+2] = (unsigned char)(o >> ((x2&3)*8)); }
      if (x3 < RBIN){ unsigned o = atomicAdd(&h[x3>>2], 1u << ((x3&3)*8));
                      epos[i+3] = (unsigned char)(o >> ((x3&3)*8)); }
    } else {
      for (int k = i; k < end; k++){
        unsigned x = (unsigned)(dst[k] - lo);
        if (x < RBIN){ unsigned o = atomicAdd(&h[x>>2], 1u << ((x&3)*8));
                       epos[k] = (unsigned char)(o >> ((x&3)*8)); }
      }
    }
  }
  __syncthreads();
  const int hi = min(RBIN, n - lo);
  unsigned* row = (unsigned*)(cnt_in + (size_t)blockIdx.x * n + lo);
  for (int j = threadIdx.x; j*4 < hi; j += 256) row[j] = h[j];
}

// ---- reduce chunk-partials: norm_src, indeg, cumB(u8), per-1024-block sums ----
__global__ __launch_bounds__(256) void k_red(const unsigned char* __restrict__ cnt_out,
    const unsigned char* __restrict__ cnt_in, float* __restrict__ norm_src,
    int* __restrict__ indeg, unsigned char* __restrict__ cumB,
    int* __restrict__ bsum, int n)
{
  __shared__ int wsums[4];
  int i0 = blockIdx.x*1024 + threadIdx.x*4;   // n % 4 == 0
  int o0=0,o1=0,o2=0,o3=0, c0=0,c1=0,c2=0,c3=0;
  if (i0 < n){
    #pragma unroll 8
    for (int b = 0; b < BCH; b++){
      unsigned wo = *(const unsigned*)(cnt_out + (size_t)b*n + i0);
      unsigned wi = *(const unsigned*)(cnt_in  + (size_t)b*n + i0);
      *(unsigned*)(cumB + (size_t)b*n + i0) =
          (unsigned)c0 | ((unsigned)c1<<8) | ((unsigned)c2<<16) | ((unsigned)c3<<24);
      o0 += wo & 0xFF; o1 += (wo>>8)&0xFF; o2 += (wo>>16)&0xFF; o3 += wo>>24;
      c0 += wi & 0xFF; c1 += (wi>>8)&0xFF; c2 += (wi>>16)&0xFF; c3 += wi>>24;
    }
    float4 ns;
    ns.x = rsqrtf((float)max(o0,1)); ns.y = rsqrtf((float)max(o1,1));
    ns.z = rsqrtf((float)max(o2,1)); ns.w = rsqrtf((float)max(o3,1));
    *(float4*)(norm_src + i0) = ns;
    int4 id; id.x=c0; id.y=c1; id.z=c2; id.w=c3;
    *(int4*)(indeg + i0) = id;
  }
  int s = c0+c1+c2+c3;
  #pragma unroll
  for (int d = 1; d < 64; d <<= 1) s += __shfl_xor(s, d);
  if ((threadIdx.x & 63) == 0) wsums[threadIdx.x>>6] = s;
  __syncthreads();
  if (threadIdx.x == 0) bsum[blockIdx.x] = wsums[0]+wsums[1]+wsums[2]+wsums[3];
}

// ---- combined weight in FRAGMENT order (per K-step, 32 x 1KB segments) ----
__global__ __launch_bounds__(256) void k_wc(const float* __restrict__ st_param,
    const float* __restrict__ weight, unsigned short* __restrict__ wcF)
{
  int idx = blockIdx.x*256 + threadIdx.x;   // 131072 total, exact grid
  int c = idx >> 9, k = idx & 511;          // c = out col (t,o), k = in row (s,f)
  int s = k >> 7, f = k & 127, t = c >> 6, o = c & 63;
  float p0 = st_param[t*4+0], p1 = st_param[t*4+1], p2 = st_param[t*4+2], p3 = st_param[t*4+3];
  float m = fmaxf(fmaxf(p0,p1), fmaxf(p2,p3));
  float e0 = expf(p0-m), e1 = expf(p1-m), e2 = expf(p2-m), e3 = expf(p3-m);
  float sum = e0+e1+e2+e3;
  float sel = (s==0)?e0:((s==1)?e1:((s==2)?e2:e3));
  float v = (sel/sum) * weight[(t*FI_+f)*FO_ + o];
  int colq = c >> 6, cq = c & 63, nn = cq >> 4, l15 = cq & 15;
  int k0s = k >> 6, kk = k & 63, ks = kk >> 5, l4 = (kk >> 3) & 3, j = kk & 7;
  int lane = l4*16 + l15;
  size_t dest = ((((size_t)(k0s*4 + colq)*2 + ks)*4 + nn)*64 + lane)*8 + j;
  wcF[dest] = f2bf(v);
}

// ---- MFMA bf16 GEMM, 128x256 tile, 8 waves (R12 structure) ----
#define GBM 128
#define GBK 64
#define ALD 72

__global__ __launch_bounds__(512) void k_gemm_mfma(
    const float* __restrict__ feat, const unsigned short* __restrict__ wcF,
    const float* __restrict__ norm_src, unsigned short* __restrict__ h2, int n)
{
  __shared__ unsigned short As[GBM][ALD];   // 18432 B, padded
  __shared__ unsigned short BsL[16384];     // 32768 B, linear fragment order
  const int row0 = blockIdx.x*GBM;
  const int t = threadIdx.x;
  const int wave = t >> 6, lane = t & 63;
  const int wr = (wave >> 2)*64;
  const int colq = wave & 3;
  const int wc = colq*64;
  const int l15 = lane & 15, l4 = lane >> 4;

  f32x4 acc[4][4] = {};

  for (int k0s = 0; k0s < KD/GBK; k0s++){
    const int k0 = k0s*GBK;
    {
      const unsigned short* gt = wcF + (size_t)k0s*16384;
      #pragma unroll
      for (int i = 0; i < 4; i++){
        int seg = wave*4 + i;
        glds16(gt + seg*512 + lane*8, BsL + seg*512);
      }
    }
    #pragma unroll
    for (int i = 0; i < 4; i++){
      int flat = t + 512*i;
      int r = flat >> 4, c4 = flat & 15;
      int gr = row0 + r;
      float4 v = {0.f,0.f,0.f,0.f};
      if (gr < n) v = *(const float4*)(feat + (size_t)gr*KD + k0 + c4*4);
      __hip_bfloat162 b01 = __float22bfloat162_rn(float2{v.x, v.y});
      __hip_bfloat162 b23 = __float22bfloat162_rn(float2{v.z, v.w});
      uint2 bw;
      bw.x = *(unsigned*)&b01; bw.y = *(unsigned*)&b23;
      *(uint2*)(&As[r][c4*4]) = bw;
    }
    __syncthreads();
    #pragma unroll
    for (int ks = 0; ks < 2; ks++){
      bf16x8 af[4], bfr[4];
      const int bbase = (colq*8 + ks*4)*512 + lane*8;
      #pragma unroll
      for (int nn = 0; nn < 4; nn++)
        bfr[nn] = *(const bf16x8*)(&BsL[bbase + nn*512]);
      #pragma unroll
      for (int m = 0; m < 4; m++)
        af[m] = *(const bf16x8*)(&As[wr + m*16 + l15][ks*32 + l4*8]);
      #pragma unroll
      for (int m = 0; m < 4; m++)
        #pragma unroll
        for (int nn = 0; nn < 4; nn++)
          acc[m][nn] = __builtin_amdgcn_mfma_f32_16x16x32_bf16(af[m], bfr[nn], acc[m][nn], 0, 0, 0);
    }
    __syncthreads();
  }
  #pragma unroll
  for (int m = 0; m < 4; m++){
    #pragma unroll
    for (int r = 0; r < 4; r++){
      int row = row0 + wr + m*16 + l4*4 + r;
      if (row < n){
        float ns = norm_src[row];
        #pragma unroll
        for (int nn = 0; nn < 4; nn++){
          int col = wc + nn*16 + l15;
          h2[(size_t)row*OD + col] = f2bf(acc[m][nn][r] * ns);
        }
      }
    }
  }
}

// ---- scan kernels ----
__global__ void k_scan2(const int* __restrict__ bsum, int* __restrict__ boff,
                        int nb, int* __restrict__ offsets, int n)
{
  int lane = threadIdx.x;  // 64 threads, 1 block
  int running = 0;
  for (int base = 0; base < nb; base += 64){
    int v = (base+lane < nb) ? bsum[base+lane] : 0;
    int x = v;
    #pragma unroll
    for (int d = 1; d < 64; d <<= 1){ int y = __shfl_up(x, d); if (lane >= d) x += y; }
    if (base+lane < nb) boff[base+lane] = running + x - v;
    running += __shfl(x, 63);
  }
  if (lane == 0) offsets[n] = running;   // = E
}

__global__ __launch_bounds__(256) void k_scan3(const int* __restrict__ cnt,
    const int* __restrict__ boff, int* __restrict__ offsets, int n)
{
  __shared__ int wsum[4], woff[4];
  int b = blockIdx.x, t = threadIdx.x, lane = t & 63, w = t >> 6;
  int base = b*1024 + t*4;
  int c[4]; int s = 0;
  #pragma unroll
  for (int i = 0; i < 4; i++){ c[i] = (base+i < n) ? cnt[base+i] : 0; s += c[i]; }
  int x = s;
  #pragma unroll
  for (int d = 1; d < 64; d <<= 1){ int y = __shfl_up(x, d); if (lane >= d) x += y; }
  if (lane == 63) wsum[w] = x;
  __syncthreads();
  if (t == 0){ int r = 0; for (int j = 0; j < 4; j++){ woff[j] = r; r += wsum[j]; } }
  __syncthreads();
  int excl = boff[b] + woff[w] + (x - s);
  #pragma unroll
  for (int i = 0; i < 4; i++){
    if (base+i < n) offsets[base+i] = excl;
    excl += c[i];
  }
}

// ---- scatter, ATOMIC-FREE (u8 metadata) ----
__global__ __launch_bounds__(256) void k_scatter(const int* __restrict__ src,
    const int* __restrict__ dst, const unsigned char* __restrict__ epos,
    const int* __restrict__ offsets, const unsigned char* __restrict__ cumB,
    int* __restrict__ esrc, int e, int n, int C)
{
  int i0 = (blockIdx.x*256 + threadIdx.x)*4;
  if (i0 + 3 < e){
    int b = i0 / C;
    const unsigned char* cb = cumB + (size_t)b*n;
    int4 a = *(const int4*)(src + i0);
    int4 d4 = *(const int4*)(dst + i0);
    unsigned pw = *(const unsigned*)(epos + i0);
    esrc[offsets[d4.x] + (int)cb[d4.x] + (int)( pw        & 0xFFu)] = a.x;
    esrc[offsets[d4.y] + (int)cb[d4.y] + (int)((pw >>  8) & 0xFFu)] = a.y;
    esrc[offsets[d4.z] + (int)cb[d4.z] + (int)((pw >> 16) & 0xFFu)] = a.z;
    esrc[offsets[d4.w] + (int)cb[d4.w] + (int)( pw >> 24        )] = a.w;
  } else {
    for (int i = i0; i < e; i++){
      int d = dst[i];
      int b = i / C;
      esrc[offsets[d] + (int)cumB[(size_t)b*n + d] + (int)epos[i]] = src[i];
    }
  }
}

// ---- aggregation, COLUMN-HALF pass: gathers 256B/edge from a 25.6MB h2 window,
//      writes 128 finalized out cols. One wave per dst node; 2 edges per round,
//      8 uint2 gathers (16 edges) in flight ----
__global__ __launch_bounds__(256) void k_agg_half(const unsigned short* __restrict__ h2,
    const int* __restrict__ offsets, const int* __restrict__ esrc,
    const float* __restrict__ bias, float* __restrict__ out, int n, int cb)
{
  int node = (blockIdx.x*256 + threadIdx.x) >> 6;
  int lane = threadIdx.x & 63;
  if (node >= n) return;
  const int half = lane >> 5;        // which edge of the pair
  const int col4 = lane & 31;        // owns cols cb + col4*4 .. +4
  int beg = offsets[node], end = offsets[node+1];

  float a0=0.f,a1=0.f,a2=0.f,a3=0.f;
  const unsigned short* hb = h2 + cb + col4*4;

  #define ACC2(V) { \
    unsigned short s0 = (unsigned short)((V).x & 0xFFFFu), s1 = (unsigned short)((V).x >> 16); \
    unsigned short s2 = (unsigned short)((V).y & 0xFFFFu), s3 = (unsigned short)((V).y >> 16); \
    a0 += bf2f(s0); a1 += bf2f(s1); a2 += bf2f(s2); a3 += bf2f(s3); }

  int i = beg;
  for (; i + 16 <= end; i += 16){
    int e0 = esrc[i      + half];
    int e1 = esrc[i +  2 + half];
    int e2 = esrc[i +  4 + half];
    int e3 = esrc[i +  6 + half];
    int e4 = esrc[i +  8 + half];
    int e5 = esrc[i + 10 + half];
    int e6 = esrc[i + 12 + half];
    int e7 = esrc[i + 14 + half];
    uint2 v0 = *(const uint2*)(hb + (size_t)e0*OD);
    uint2 v1 = *(const uint2*)(hb + (size_t)e1*OD);
    uint2 v2 = *(const uint2*)(hb + (size_t)e2*OD);
    uint2 v3 = *(const uint2*)(hb + (size_t)e3*OD);
    uint2 v4 = *(const uint2*)(hb + (size_t)e4*OD);
    uint2 v5 = *(const uint2*)(hb + (size_t)e5*OD);
    uint2 v6 = *(const uint2*)(hb + (size_t)e6*OD);
    uint2 v7 = *(const uint2*)(hb + (size_t)e7*OD);
    ACC2(v0); ACC2(v1); ACC2(v2); ACC2(v3);
    ACC2(v4); ACC2(v5); ACC2(v6); ACC2(v7);
  }
  for (; i + 2 <= end; i += 2){
    int e = esrc[i + half];
    uint2 v = *(const uint2*)(hb + (size_t)e*OD);
    ACC2(v);
  }
  if (i < end && half == 0){
    int e = esrc[i];
    uint2 v = *(const uint2*)(hb + (size_t)e*OD);
    ACC2(v);
  }
  #undef ACC2

  a0 += __shfl_xor(a0, 32); a1 += __shfl_xor(a1, 32);
  a2 += __shfl_xor(a2, 32); a3 += __shfl_xor(a3, 32);

  if (half == 0){
    int d = end - beg; if (d < 1) d = 1;
    float nd = rsqrtf((float)d);
    int c0 = cb + col4*4;
    const float* bz = bias + c0;
    float4 o;
    o.x = a0*nd + bz[0]; o.y = a1*nd + bz[1];
    o.z = a2*nd + bz[2]; o.w = a3*nd + bz[3];
    *(float4*)(out + (size_t)node*OD + c0) = o;
  }
}

extern "C" void kernel_launch(void* const* d_in, const int* in_sizes, int n_in,
                              void* d_out, int out_size, void* d_ws, size_t ws_size,
                              hipStream_t stream)
{
  const float* feat     = (const float*)d_in[0];
  const float* weight   = (const float*)d_in[1];
  const float* bias     = (const float*)d_in[2];
  const float* st_param = (const float*)d_in[3];
  const int*   src      = (const int*)d_in[4];
  const int*   dst      = (const int*)d_in[5];
  const int N = in_sizes[0] / KD;
  const int E = in_sizes[4];

  char* w = (char*)d_ws;
  size_t off = 0;
  auto take = [&](size_t bytes) -> char* {
    char* p = w + off;
    off = (off + bytes + 255) & ~(size_t)255;
    return p;
  };
  unsigned char* cnt_out = (unsigned char*)take((size_t)BCH*N);
  unsigned char* cnt_in  = (unsigned char*)take((size_t)BCH*N);
  unsigned char* cumB    = (unsigned char*)take((size_t)BCH*N);
  unsigned char* epos    = (unsigned char*)take((size_t)E);
  int* indeg    = (int*)take((size_t)N*4);
  int* offsets  = (int*)take((size_t)(N+1)*4);
  int* bsum     = (int*)take(512*4);
  int* boff     = (int*)take(512*4);
  float* norm_src = (float*)take((size_t)N*4);
  unsigned short* wcF = (unsigned short*)take((size_t)KD*OD*2);
  int* esrc     = (int*)take((size_t)E*4);
  unsigned short* h2 = (unsigned short*)take((size_t)N*OD*2);
  (void)ws_size; (void)out_size; (void)n_in;

  float* out = (float*)d_out;

  int C = (((E + BCH - 1)/BCH) + 1023) & ~1023;
  int nparts = (N + RBIN - 1)/RBIN;   // = 2
  dim3 gh(BCH, nparts);
  k_hist_out<<<gh, 256, 0, stream>>>(src, cnt_out, E, N, C);
  k_hist_in <<<gh, 256, 0, stream>>>(dst, cnt_in, epos, E, N, C);
  k_wc<<<(KD*OD)/256, 256, 0, stream>>>(st_param, weight, wcF);
  int nb = (N + 1023)/1024;
  k_red<<<nb, 256, 0, stream>>>(cnt_out, cnt_in, norm_src, indeg, cumB, bsum, N);
  k_gemm_mfma<<<(N+GBM-1)/GBM, 512, 0, stream>>>(feat, wcF, norm_src, h2, N);
  k_scan2<<<1, 64, 0, stream>>>(bsum, boff, nb, offsets, N);
  k_scan3<<<nb, 256, 0, stream>>>(indeg, boff, offsets, N);
  int eb4 = (E + 1023)/1024;
  k_scatter<<<eb4, 256, 0, stream>>>(src, dst, epos, offsets, cumB, esrc, E, N, C);
  k_agg_half<<<(N+3)/4, 256, 0, stream>>>(h2, offsets, esrc, bias, out, N, 0);
  k_agg_half<<<(N+3)/4, 256, 0, stream>>>(h2, offsets, esrc, bias, out, N, 128);
}

// Round 14
// 423.471 us; speedup vs baseline: 1.0565x; 1.0565x over previous
//
#include <hip/hip_runtime.h>
#include <hip/hip_bf16.h>

#define T_ 4
#define FI_ 128
#define FO_ 64
#define KD 512     // T*FI
#define OD 256     // T*FO

#define RBIN 65536 // u8-packed LDS histogram bins per partition (64 KB)
#define RBW (RBIN/4)
#define BCH 128    // edge chunks (= rank-partial rows)

typedef __attribute__((ext_vector_type(8))) short bf16x8;
typedef __attribute__((ext_vector_type(4))) float f32x4;

static __device__ __forceinline__ float bf2f(unsigned short u){
  return __uint_as_float(((unsigned int)u) << 16);
}
static __device__ __forceinline__ unsigned short f2bf(float f){
  unsigned int u = __float_as_uint(f);
  u += 0x7FFFu + ((u >> 16) & 1u);
  return (unsigned short)(u >> 16);
}
// async global->LDS, 16B per lane; LDS dest = uniform base + lane*16 (linear)
static __device__ __forceinline__ void glds16(const void* g, void* l){
  __builtin_amdgcn_global_load_lds(
    (const __attribute__((address_space(1))) unsigned int*)g,
    (__attribute__((address_space(3))) unsigned int*)l, 16, 0, 0);
}

// ---- outdeg histogram (blockIdx.y < nparts) FUSED with wcF build (blockIdx.y >= nparts).
//      wc planes run concurrently with hist planes; they exit before touching LDS. ----
__global__ __launch_bounds__(256) void k_hist_out(const int* __restrict__ src,
    unsigned char* __restrict__ cnt_out, int e, int n, int C, int nparts,
    const float* __restrict__ st_param, const float* __restrict__ weight,
    unsigned short* __restrict__ wcF)
{
  if ((int)blockIdx.y >= nparts){
    // ---- wcF build: 131072 elements, 2 per thread ----
    int base = ((int)blockIdx.y - nparts)*(int)gridDim.x*256 + blockIdx.x*256 + threadIdx.x;
    #pragma unroll
    for (int rep = 0; rep < 2; rep++){
      int idx = base + rep*65536;     // covers 131072 with gridDim.x=128, 2 planes... adjust host side
      if (idx < KD*OD){
        int c = idx >> 9, k = idx & 511;
        int s = k >> 7, f = k & 127, t = c >> 6, o = c & 63;
        float p0 = st_param[t*4+0], p1 = st_param[t*4+1], p2 = st_param[t*4+2], p3 = st_param[t*4+3];
        float m = fmaxf(fmaxf(p0,p1), fmaxf(p2,p3));
        float e0 = expf(p0-m), e1 = expf(p1-m), e2 = expf(p2-m), e3 = expf(p3-m);
        float sum = e0+e1+e2+e3;
        float sel = (s==0)?e0:((s==1)?e1:((s==2)?e2:e3));
        float v = (sel/sum) * weight[(t*FI_+f)*FO_ + o];
        int colq = c >> 6, cq = c & 63, nn = cq >> 4, l15 = cq & 15;
        int k0s = k >> 6, kk = k & 63, ks = kk >> 5, l4 = (kk >> 3) & 3, j = kk & 7;
        int lane = l4*16 + l15;
        size_t dest = ((((size_t)(k0s*4 + colq)*2 + ks)*4 + nn)*64 + lane)*8 + j;
        wcF[dest] = f2bf(v);
      }
    }
    return;
  }
  __shared__ unsigned h[RBW];
  for (int j = threadIdx.x; j < RBW; j += 256) h[j] = 0;
  __syncthreads();
  const int lo  = blockIdx.y * RBIN;
  const int beg = blockIdx.x * C;
  const int end = min(beg + C, e);
  for (int i = beg + (int)threadIdx.x*4; i < end; i += 1024){
    if (i + 3 < end){
      int4 s4 = *(const int4*)(src + i);
      unsigned x0 = (unsigned)(s4.x - lo), x1 = (unsigned)(s4.y - lo);
      unsigned x2 = (unsigned)(s4.z - lo), x3 = (unsigned)(s4.w - lo);
      if (x0 < RBIN) atomicAdd(&h[x0>>2], 1u << ((x0&3)*8));
      if (x1 < RBIN) atomicAdd(&h[x1>>2], 1u << ((x1&3)*8));
      if (x2 < RBIN) atomicAdd(&h[x2>>2], 1u << ((x2&3)*8));
      if (x3 < RBIN) atomicAdd(&h[x3>>2], 1u << ((x3&3)*8));
    } else {
      for (int k = i; k < end; k++){
        unsigned x = (unsigned)(src[k] - lo);
        if (x < RBIN) atomicAdd(&h[x>>2], 1u << ((x&3)*8));
      }
    }
  }
  __syncthreads();
  const int hi = min(RBIN, n - lo);
  unsigned* row = (unsigned*)(cnt_out + (size_t)blockIdx.x * n + lo);
  for (int j = threadIdx.x; j*4 < hi; j += 256) row[j] = h[j];
}

// ---- indeg histogram + per-edge u8 rank (packed LDS fetch_add) ----
__global__ __launch_bounds__(256) void k_hist_in(const int* __restrict__ dst,
    unsigned char* __restrict__ cnt_in, unsigned char* __restrict__ epos,
    int e, int n, int C)
{
  __shared__ unsigned h[RBW];
  for (int j = threadIdx.x; j < RBW; j += 256) h[j] = 0;
  __syncthreads();
  const int lo  = blockIdx.y * RBIN;
  const int beg = blockIdx.x * C;
  const int end = min(beg + C, e);
  for (int i = beg + (int)threadIdx.x*4; i < end; i += 1024){
    if (i + 3 < end){
      int4 d4 = *(const int4*)(dst + i);
      unsigned x0 = (unsigned)(d4.x - lo), x1 = (unsigned)(d4.y - lo);
      unsigned x2 = (unsigned)(d4.z - lo), x3 = (unsigned)(d4.w - lo);
      if (x0 < RBIN){ unsigned o = atomicAdd(&h[x0>>2], 1u << ((x0&3)*8));
                      epos[i  ] = (unsigned char)(o >> ((x0&3)*8)); }
      if (x1 < RBIN){ unsigned o = atomicAdd(&h[x1>>2], 1u << ((x1&3)*8));
                      epos[i+1] = (unsigned char)(o >> ((x1&3)*8)); }
      if (x2 < RBIN){ unsigned o = atomicAdd(&h[x2>>2], 1u << ((x2&3)*8));
                      epos[i+2] = (unsigned char)(o >> ((x2&3)*8)); }
      if (x3 < RBIN){ unsigned o = atomicAdd(&h[x3>>2], 1u << ((x3&3)*8));
                      epos[i+3] = (unsigned char)(o >> ((x3&3)*8)); }
    } else {
      for (int k = i; k < end; k++){
        unsigned x = (unsigned)(dst[k] - lo);
        if (x < RBIN){ unsigned o = atomicAdd(&h[x>>2], 1u << ((x&3)*8));
                       epos[k] = (unsigned char)(o >> ((x&3)*8)); }
      }
    }
  }
  __syncthreads();
  const int hi = min(RBIN, n - lo);
  unsigned* row = (unsigned*)(cnt_in + (size_t)blockIdx.x * n + lo);
  for (int j = threadIdx.x; j*4 < hi; j += 256) row[j] = h[j];
}

// ---- reduce chunk-partials: norm_src, indeg, cumB(u8), per-1024-block sums ----
__global__ __launch_bounds__(256) void k_red(const unsigned char* __restrict__ cnt_out,
    const unsigned char* __restrict__ cnt_in, float* __restrict__ norm_src,
    int* __restrict__ indeg, unsigned char* __restrict__ cumB,
    int* __restrict__ bsum, int n)
{
  __shared__ int wsums[4];
  int i0 = blockIdx.x*1024 + threadIdx.x*4;   // n % 4 == 0
  int o0=0,o1=0,o2=0,o3=0, c0=0,c1=0,c2=0,c3=0;
  if (i0 < n){
    #pragma unroll 8
    for (int b = 0; b < BCH; b++){
      unsigned wo = *(const unsigned*)(cnt_out + (size_t)b*n + i0);
      unsigned wi = *(const unsigned*)(cnt_in  + (size_t)b*n + i0);
      *(unsigned*)(cumB + (size_t)b*n + i0) =
          (unsigned)c0 | ((unsigned)c1<<8) | ((unsigned)c2<<16) | ((unsigned)c3<<24);
      o0 += wo & 0xFF; o1 += (wo>>8)&0xFF; o2 += (wo>>16)&0xFF; o3 += wo>>24;
      c0 += wi & 0xFF; c1 += (wi>>8)&0xFF; c2 += (wi>>16)&0xFF; c3 += wi>>24;
    }
    float4 ns;
    ns.x = rsqrtf((float)max(o0,1)); ns.y = rsqrtf((float)max(o1,1));
    ns.z = rsqrtf((float)max(o2,1)); ns.w = rsqrtf((float)max(o3,1));
    *(float4*)(norm_src + i0) = ns;
    int4 id; id.x=c0; id.y=c1; id.z=c2; id.w=c3;
    *(int4*)(indeg + i0) = id;
  }
  int s = c0+c1+c2+c3;
  #pragma unroll
  for (int d = 1; d < 64; d <<= 1) s += __shfl_xor(s, d);
  if ((threadIdx.x & 63) == 0) wsums[threadIdx.x>>6] = s;
  __syncthreads();
  if (threadIdx.x == 0) bsum[blockIdx.x] = wsums[0]+wsums[1]+wsums[2]+wsums[3];
}

// ---- MFMA bf16 GEMM, 128x256 tile, 8 waves (R12 structure) ----
#define GBM 128
#define GBK 64
#define ALD 72

__global__ __launch_bounds__(512) void k_gemm_mfma(
    const float* __restrict__ feat, const unsigned short* __restrict__ wcF,
    const float* __restrict__ norm_src, unsigned short* __restrict__ h2, int n)
{
  __shared__ unsigned short As[GBM][ALD];   // 18432 B, padded
  __shared__ unsigned short BsL[16384];     // 32768 B, linear fragment order
  const int row0 = blockIdx.x*GBM;
  const int t = threadIdx.x;
  const int wave = t >> 6, lane = t & 63;
  const int wr = (wave >> 2)*64;
  const int colq = wave & 3;
  const int wc = colq*64;
  const int l15 = lane & 15, l4 = lane >> 4;

  f32x4 acc[4][4] = {};

  for (int k0s = 0; k0s < KD/GBK; k0s++){
    const int k0 = k0s*GBK;
    {
      const unsigned short* gt = wcF + (size_t)k0s*16384;
      #pragma unroll
      for (int i = 0; i < 4; i++){
        int seg = wave*4 + i;
        glds16(gt + seg*512 + lane*8, BsL + seg*512);
      }
    }
    #pragma unroll
    for (int i = 0; i < 4; i++){
      int flat = t + 512*i;
      int r = flat >> 4, c4 = flat & 15;
      int gr = row0 + r;
      float4 v = {0.f,0.f,0.f,0.f};
      if (gr < n) v = *(const float4*)(feat + (size_t)gr*KD + k0 + c4*4);
      __hip_bfloat162 b01 = __float22bfloat162_rn(float2{v.x, v.y});
      __hip_bfloat162 b23 = __float22bfloat162_rn(float2{v.z, v.w});
      uint2 bw;
      bw.x = *(unsigned*)&b01; bw.y = *(unsigned*)&b23;
      *(uint2*)(&As[r][c4*4]) = bw;
    }
    __syncthreads();
    #pragma unroll
    for (int ks = 0; ks < 2; ks++){
      bf16x8 af[4], bfr[4];
      const int bbase = (colq*8 + ks*4)*512 + lane*8;
      #pragma unroll
      for (int nn = 0; nn < 4; nn++)
        bfr[nn] = *(const bf16x8*)(&BsL[bbase + nn*512]);
      #pragma unroll
      for (int m = 0; m < 4; m++)
        af[m] = *(const bf16x8*)(&As[wr + m*16 + l15][ks*32 + l4*8]);
      #pragma unroll
      for (int m = 0; m < 4; m++)
        #pragma unroll
        for (int nn = 0; nn < 4; nn++)
          acc[m][nn] = __builtin_amdgcn_mfma_f32_16x16x32_bf16(af[m], bfr[nn], acc[m][nn], 0, 0, 0);
    }
    __syncthreads();
  }
  #pragma unroll
  for (int m = 0; m < 4; m++){
    #pragma unroll
    for (int r = 0; r < 4; r++){
      int row = row0 + wr + m*16 + l4*4 + r;
      if (row < n){
        float ns = norm_src[row];
        #pragma unroll
        for (int nn = 0; nn < 4; nn++){
          int col = wc + nn*16 + l15;
          h2[(size_t)row*OD + col] = f2bf(acc[m][nn][r] * ns);
        }
      }
    }
  }
}

// ---- scan kernels ----
__global__ void k_scan2(const int* __restrict__ bsum, int* __restrict__ boff,
                        int nb, int* __restrict__ offsets, int n)
{
  int lane = threadIdx.x;  // 64 threads, 1 block
  int running = 0;
  for (int base = 0; base < nb; base += 64){
    int v = (base+lane < nb) ? bsum[base+lane] : 0;
    int x = v;
    #pragma unroll
    for (int d = 1; d < 64; d <<= 1){ int y = __shfl_up(x, d); if (lane >= d) x += y; }
    if (base+lane < nb) boff[base+lane] = running + x - v;
    running += __shfl(x, 63);
  }
  if (lane == 0) offsets[n] = running;   // = E
}

__global__ __launch_bounds__(256) void k_scan3(const int* __restrict__ cnt,
    const int* __restrict__ boff, int* __restrict__ offsets, int n)
{
  __shared__ int wsum[4], woff[4];
  int b = blockIdx.x, t = threadIdx.x, lane = t & 63, w = t >> 6;
  int base = b*1024 + t*4;
  int c[4]; int s = 0;
  #pragma unroll
  for (int i = 0; i < 4; i++){ c[i] = (base+i < n) ? cnt[base+i] : 0; s += c[i]; }
  int x = s;
  #pragma unroll
  for (int d = 1; d < 64; d <<= 1){ int y = __shfl_up(x, d); if (lane >= d) x += y; }
  if (lane == 63) wsum[w] = x;
  __syncthreads();
  if (t == 0){ int r = 0; for (int j = 0; j < 4; j++){ woff[j] = r; r += wsum[j]; } }
  __syncthreads();
  int excl = boff[b] + woff[w] + (x - s);
  #pragma unroll
  for (int i = 0; i < 4; i++){
    if (base+i < n) offsets[base+i] = excl;
    excl += c[i];
  }
}

// ---- scatter, ATOMIC-FREE (u8 metadata) ----
__global__ __launch_bounds__(256) void k_scatter(const int* __restrict__ src,
    const int* __restrict__ dst, const unsigned char* __restrict__ epos,
    const int* __restrict__ offsets, const unsigned char* __restrict__ cumB,
    int* __restrict__ esrc, int e, int n, int C)
{
  int i0 = (blockIdx.x*256 + threadIdx.x)*4;
  if (i0 + 3 < e){
    int b = i0 / C;
    const unsigned char* cb = cumB + (size_t)b*n;
    int4 a = *(const int4*)(src + i0);
    int4 d4 = *(const int4*)(dst + i0);
    unsigned pw = *(const unsigned*)(epos + i0);
    esrc[offsets[d4.x] + (int)cb[d4.x] + (int)( pw        & 0xFFu)] = a.x;
    esrc[offsets[d4.y] + (int)cb[d4.y] + (int)((pw >>  8) & 0xFFu)] = a.y;
    esrc[offsets[d4.z] + (int)cb[d4.z] + (int)((pw >> 16) & 0xFFu)] = a.z;
    esrc[offsets[d4.w] + (int)cb[d4.w] + (int)( pw >> 24        )] = a.w;
  } else {
    for (int i = i0; i < e; i++){
      int d = dst[i];
      int b = i / C;
      esrc[offsets[d] + (int)cumB[(size_t)b*n + d] + (int)epos[i]] = src[i];
    }
  }
}

// ---- aggregation: one wave per dst node; 16 edges (8 KB) in flight per wave ----
__global__ __launch_bounds__(256) void k_agg(const unsigned short* __restrict__ h2,
    const int* __restrict__ offsets, const int* __restrict__ esrc,
    const float* __restrict__ bias, float* __restrict__ out, int n)
{
  int node = (blockIdx.x*256 + threadIdx.x) >> 6;
  int lane = threadIdx.x & 63;
  if (node >= n) return;
  const int half = lane >> 5;        // which edge of the pair
  const int col8 = lane & 31;        // owns cols [col8*8, col8*8+8)
  int beg = offsets[node], end = offsets[node+1];

  float a0=0.f,a1=0.f,a2=0.f,a3=0.f,a4=0.f,a5=0.f,a6=0.f,a7=0.f;

  #define ACC(V) { \
    unsigned short s0 = (unsigned short)((V).x & 0xFFFFu), s1 = (unsigned short)((V).x >> 16); \
    unsigned short s2 = (unsigned short)((V).y & 0xFFFFu), s3 = (unsigned short)((V).y >> 16); \
    unsigned short s4 = (unsigned short)((V).z & 0xFFFFu), s5 = (unsigned short)((V).z >> 16); \
    unsigned short s6 = (unsigned short)((V).w & 0xFFFFu), s7 = (unsigned short)((V).w >> 16); \
    a0 += bf2f(s0); a1 += bf2f(s1); a2 += bf2f(s2); a3 += bf2f(s3); \
    a4 += bf2f(s4); a5 += bf2f(s5); a6 += bf2f(s6); a7 += bf2f(s7); }

  int i = beg;
  for (; i + 16 <= end; i += 16){
    int e0 = esrc[i      + half];
    int e1 = esrc[i +  2 + half];
    int e2 = esrc[i +  4 + half];
    int e3 = esrc[i +  6 + half];
    int e4 = esrc[i +  8 + half];
    int e5 = esrc[i + 10 + half];
    int e6 = esrc[i + 12 + half];
    int e7 = esrc[i + 14 + half];
    uint4 v0 = *(const uint4*)(h2 + (size_t)e0*OD + col8*8);
    uint4 v1 = *(const uint4*)(h2 + (size_t)e1*OD + col8*8);
    uint4 v2 = *(const uint4*)(h2 + (size_t)e2*OD + col8*8);
    uint4 v3 = *(const uint4*)(h2 + (size_t)e3*OD + col8*8);
    uint4 v4 = *(const uint4*)(h2 + (size_t)e4*OD + col8*8);
    uint4 v5 = *(const uint4*)(h2 + (size_t)e5*OD + col8*8);
    uint4 v6 = *(const uint4*)(h2 + (size_t)e6*OD + col8*8);
    uint4 v7 = *(const uint4*)(h2 + (size_t)e7*OD + col8*8);
    ACC(v0); ACC(v1); ACC(v2); ACC(v3);
    ACC(v4); ACC(v5); ACC(v6); ACC(v7);
  }
  for (; i + 2 <= end; i += 2){
    int e = esrc[i + half];
    uint4 v = *(const uint4*)(h2 + (size_t)e*OD + col8*8);
    ACC(v);
  }
  if (i < end && half == 0){
    int e = esrc[i];
    uint4 v = *(const uint4*)(h2 + (size_t)e*OD + col8*8);
    ACC(v);
  }
  #undef ACC

  a0 += __shfl_xor(a0, 32); a1 += __shfl_xor(a1, 32);
  a2 += __shfl_xor(a2, 32); a3 += __shfl_xor(a3, 32);
  a4 += __shfl_xor(a4, 32); a5 += __shfl_xor(a5, 32);
  a6 += __shfl_xor(a6, 32); a7 += __shfl_xor(a7, 32);

  int d = end - beg; if (d < 1) d = 1;
  float nd = rsqrtf((float)d);
  int c0 = col8*8 + half*4;
  const float* bz = bias + c0;
  float4 o;
  if (half == 0){
    o.x = a0*nd + bz[0]; o.y = a1*nd + bz[1];
    o.z = a2*nd + bz[2]; o.w = a3*nd + bz[3];
  } else {
    o.x = a4*nd + bz[0]; o.y = a5*nd + bz[1];
    o.z = a6*nd + bz[2]; o.w = a7*nd + bz[3];
  }
  *(float4*)(out + (size_t)node*OD + c0) = o;
}

extern "C" void kernel_launch(void* const* d_in, const int* in_sizes, int n_in,
                              void* d_out, int out_size, void* d_ws, size_t ws_size,
                              hipStream_t stream)
{
  const float* feat     = (const float*)d_in[0];
  const float* weight   = (const float*)d_in[1];
  const float* bias     = (const float*)d_in[2];
  const float* st_param = (const float*)d_in[3];
  const int*   src      = (const int*)d_in[4];
  const int*   dst      = (const int*)d_in[5];
  const int N = in_sizes[0] / KD;
  const int E = in_sizes[4];

  char* w = (char*)d_ws;
  size_t off = 0;
  auto take = [&](size_t bytes) -> char* {
    char* p = w + off;
    off = (off + bytes + 255) & ~(size_t)255;
    return p;
  };
  unsigned char* cnt_out = (unsigned char*)take((size_t)BCH*N);
  unsigned char* cnt_in  = (unsigned char*)take((size_t)BCH*N);
  unsigned char* cumB    = (unsigned char*)take((size_t)BCH*N);
  unsigned char* epos    = (unsigned char*)take((size_t)E);
  int* indeg    = (int*)take((size_t)N*4);
  int* offsets  = (int*)take((size_t)(N+1)*4);
  int* bsum     = (int*)take(512*4);
  int* boff     = (int*)take(512*4);
  float* norm_src = (float*)take((size_t)N*4);
  unsigned short* wcF = (unsigned short*)take((size_t)KD*OD*2);
  int* esrc     = (int*)take((size_t)E*4);
  unsigned short* h2 = (unsigned short*)take((size_t)N*OD*2);
  (void)ws_size; (void)out_size; (void)n_in;

  float* out = (float*)d_out;

  int C = (((E + BCH - 1)/BCH) + 1023) & ~1023;
  int nparts = (N + RBIN - 1)/RBIN;   // = 2
  // hist_out grid: nparts hist planes + 2 wc planes (128 blocks * 256 thr * 2 planes * 2 reps = 131072)
  dim3 gho(BCH, nparts + 2);
  k_hist_out<<<gho, 256, 0, stream>>>(src, cnt_out, E, N, C, nparts, st_param, weight, wcF);
  dim3 ghi(BCH, nparts);
  k_hist_in <<<ghi, 256, 0, stream>>>(dst, cnt_in, epos, E, N, C);
  int nb = (N + 1023)/1024;
  k_red<<<nb, 256, 0, stream>>>(cnt_out, cnt_in, norm_src, indeg, cumB, bsum, N);
  k_scan2<<<1, 64, 0, stream>>>(bsum, boff, nb, offsets, N);
  k_scan3<<<nb, 256, 0, stream>>>(indeg, boff, offsets, N);
  int eb4 = (E + 1023)/1024;
  k_scatter<<<eb4, 256, 0, stream>>>(src, dst, epos, offsets, cumB, esrc, E, N, C);
  k_gemm_mfma<<<(N+GBM-1)/GBM, 512, 0, stream>>>(feat, wcF, norm_src, h2, N);
  k_agg<<<(N+3)/4, 256, 0, stream>>>(h2, offsets, esrc, bias, out, N);
}

// Round 15
// 361.086 us; speedup vs baseline: 1.2390x; 1.1728x over previous
//
#include <hip/hip_runtime.h>
#include <hip/hip_bf16.h>

#define T_ 4
#define FI_ 128
#define FO_ 64
#define KD 512     // T*FI
#define OD 256     // T*FO

#define RBIN 65536 // u8-packed LDS histogram bins per partition (64 KB)
#define RBW (RBIN/4)
#define BCH 128    // edge chunks (= rank-partial rows)

typedef __attribute__((ext_vector_type(8))) short bf16x8;
typedef __attribute__((ext_vector_type(4))) float f32x4;

static __device__ __forceinline__ float bf2f(unsigned short u){
  return __uint_as_float(((unsigned int)u) << 16);
}
static __device__ __forceinline__ unsigned short f2bf(float f){
  unsigned int u = __float_as_uint(f);
  u += 0x7FFFu + ((u >> 16) & 1u);
  return (unsigned short)(u >> 16);
}
// async global->LDS, 16B per lane; LDS dest = uniform base + lane*16 (linear)
static __device__ __forceinline__ void glds16(const void* g, void* l){
  __builtin_amdgcn_global_load_lds(
    (const __attribute__((address_space(1))) unsigned int*)g,
    (__attribute__((address_space(3))) unsigned int*)l, 16, 0, 0);
}

// ---- outdeg histogram (blockIdx.y < nparts) FUSED with wcF build (blockIdx.y >= nparts) ----
__global__ __launch_bounds__(256) void k_hist_out(const int* __restrict__ src,
    unsigned char* __restrict__ cnt_out, int e, int n, int C, int nparts,
    const float* __restrict__ st_param, const float* __restrict__ weight,
    unsigned short* __restrict__ wcF)
{
  if ((int)blockIdx.y >= nparts){
    int base = ((int)blockIdx.y - nparts)*(int)gridDim.x*256 + blockIdx.x*256 + threadIdx.x;
    #pragma unroll
    for (int rep = 0; rep < 2; rep++){
      int idx = base + rep*65536;
      if (idx < KD*OD){
        int c = idx >> 9, k = idx & 511;
        int s = k >> 7, f = k & 127, t = c >> 6, o = c & 63;
        float p0 = st_param[t*4+0], p1 = st_param[t*4+1], p2 = st_param[t*4+2], p3 = st_param[t*4+3];
        float m = fmaxf(fmaxf(p0,p1), fmaxf(p2,p3));
        float e0 = expf(p0-m), e1 = expf(p1-m), e2 = expf(p2-m), e3 = expf(p3-m);
        float sum = e0+e1+e2+e3;
        float sel = (s==0)?e0:((s==1)?e1:((s==2)?e2:e3));
        float v = (sel/sum) * weight[(t*FI_+f)*FO_ + o];
        int colq = c >> 6, cq = c & 63, nn = cq >> 4, l15 = cq & 15;
        int k0s = k >> 6, kk = k & 63, ks = kk >> 5, l4 = (kk >> 3) & 3, j = kk & 7;
        int lane = l4*16 + l15;
        size_t dest = ((((size_t)(k0s*4 + colq)*2 + ks)*4 + nn)*64 + lane)*8 + j;
        wcF[dest] = f2bf(v);
      }
    }
    return;
  }
  __shared__ unsigned h[RBW];
  for (int j = threadIdx.x; j < RBW; j += 256) h[j] = 0;
  __syncthreads();
  const int lo  = blockIdx.y * RBIN;
  const int beg = blockIdx.x * C;
  const int end = min(beg + C, e);
  for (int i = beg + (int)threadIdx.x*4; i < end; i += 1024){
    if (i + 3 < end){
      int4 s4 = *(const int4*)(src + i);
      unsigned x0 = (unsigned)(s4.x - lo), x1 = (unsigned)(s4.y - lo);
      unsigned x2 = (unsigned)(s4.z - lo), x3 = (unsigned)(s4.w - lo);
      if (x0 < RBIN) atomicAdd(&h[x0>>2], 1u << ((x0&3)*8));
      if (x1 < RBIN) atomicAdd(&h[x1>>2], 1u << ((x1&3)*8));
      if (x2 < RBIN) atomicAdd(&h[x2>>2], 1u << ((x2&3)*8));
      if (x3 < RBIN) atomicAdd(&h[x3>>2], 1u << ((x3&3)*8));
    } else {
      for (int k = i; k < end; k++){
        unsigned x = (unsigned)(src[k] - lo);
        if (x < RBIN) atomicAdd(&h[x>>2], 1u << ((x&3)*8));
      }
    }
  }
  __syncthreads();
  const int hi = min(RBIN, n - lo);
  unsigned* row = (unsigned*)(cnt_out + (size_t)blockIdx.x * n + lo);
  for (int j = threadIdx.x; j*4 < hi; j += 256) row[j] = h[j];
}

// ---- indeg histogram + per-edge u8 rank (packed LDS fetch_add) ----
__global__ __launch_bounds__(256) void k_hist_in(const int* __restrict__ dst,
    unsigned char* __restrict__ cnt_in, unsigned char* __restrict__ epos,
    int e, int n, int C)
{
  __shared__ unsigned h[RBW];
  for (int j = threadIdx.x; j < RBW; j += 256) h[j] = 0;
  __syncthreads();
  const int lo  = blockIdx.y * RBIN;
  const int beg = blockIdx.x * C;
  const int end = min(beg + C, e);
  for (int i = beg + (int)threadIdx.x*4; i < end; i += 1024){
    if (i + 3 < end){
      int4 d4 = *(const int4*)(dst + i);
      unsigned x0 = (unsigned)(d4.x - lo), x1 = (unsigned)(d4.y - lo);
      unsigned x2 = (unsigned)(d4.z - lo), x3 = (unsigned)(d4.w - lo);
      if (x0 < RBIN){ unsigned o = atomicAdd(&h[x0>>2], 1u << ((x0&3)*8));
                      epos[i  ] = (unsigned char)(o >> ((x0&3)*8)); }
      if (x1 < RBIN){ unsigned o = atomicAdd(&h[x1>>2], 1u << ((x1&3)*8));
                      epos[i+1] = (unsigned char)(o >> ((x1&3)*8)); }
      if (x2 < RBIN){ unsigned o = atomicAdd(&h[x2>>2], 1u << ((x2&3)*8));
                      epos[i+2] = (unsigned char)(o >> ((x2&3)*8)); }
      if (x3 < RBIN){ unsigned o = atomicAdd(&h[x3>>2], 1u << ((x3&3)*8));
                      epos[i+3] = (unsigned char)(o >> ((x3&3)*8)); }
    } else {
      for (int k = i; k < end; k++){
        unsigned x = (unsigned)(dst[k] - lo);
        if (x < RBIN){ unsigned o = atomicAdd(&h[x>>2], 1u << ((x&3)*8));
                       epos[k] = (unsigned char)(o >> ((x&3)*8)); }
      }
    }
  }
  __syncthreads();
  const int hi = min(RBIN, n - lo);
  unsigned* row = (unsigned*)(cnt_in + (size_t)blockIdx.x * n + lo);
  for (int j = threadIdx.x; j*4 < hi; j += 256) row[j] = h[j];
}

// ---- reduce chunk-partials: norm_src, indeg, cumB(u8), per-1024-block sums ----
__global__ __launch_bounds__(256) void k_red(const unsigned char* __restrict__ cnt_out,
    const unsigned char* __restrict__ cnt_in, float* __restrict__ norm_src,
    int* __restrict__ indeg, unsigned char* __restrict__ cumB,
    int* __restrict__ bsum, int n)
{
  __shared__ int wsums[4];
  int i0 = blockIdx.x*1024 + threadIdx.x*4;   // n % 4 == 0
  int o0=0,o1=0,o2=0,o3=0, c0=0,c1=0,c2=0,c3=0;
  if (i0 < n){
    #pragma unroll 8
    for (int b = 0; b < BCH; b++){
      unsigned wo = *(const unsigned*)(cnt_out + (size_t)b*n + i0);
      unsigned wi = *(const unsigned*)(cnt_in  + (size_t)b*n + i0);
      *(unsigned*)(cumB + (size_t)b*n + i0) =
          (unsigned)c0 | ((unsigned)c1<<8) | ((unsigned)c2<<16) | ((unsigned)c3<<24);
      o0 += wo & 0xFF; o1 += (wo>>8)&0xFF; o2 += (wo>>16)&0xFF; o3 += wo>>24;
      c0 += wi & 0xFF; c1 += (wi>>8)&0xFF; c2 += (wi>>16)&0xFF; c3 += wi>>24;
    }
    float4 ns;
    ns.x = rsqrtf((float)max(o0,1)); ns.y = rsqrtf((float)max(o1,1));
    ns.z = rsqrtf((float)max(o2,1)); ns.w = rsqrtf((float)max(o3,1));
    *(float4*)(norm_src + i0) = ns;
    int4 id; id.x=c0; id.y=c1; id.z=c2; id.w=c3;
    *(int4*)(indeg + i0) = id;
  }
  int s = c0+c1+c2+c3;
  #pragma unroll
  for (int d = 1; d < 64; d <<= 1) s += __shfl_xor(s, d);
  if ((threadIdx.x & 63) == 0) wsums[threadIdx.x>>6] = s;
  __syncthreads();
  if (threadIdx.x == 0) bsum[blockIdx.x] = wsums[0]+wsums[1]+wsums[2]+wsums[3];
}

// ---- MFMA bf16 GEMM, 128x256 tile, 8 waves; h2 emitted as INT8 + per-row scale ----
#define GBM 128
#define GBK 64
#define ALD 72

__global__ __launch_bounds__(512) void k_gemm_mfma(
    const float* __restrict__ feat, const unsigned short* __restrict__ wcF,
    const float* __restrict__ norm_src, signed char* __restrict__ h2,
    float* __restrict__ scales, int n)
{
  __shared__ unsigned short As[GBM][ALD];   // 18432 B, padded
  __shared__ unsigned short BsL[16384];     // 32768 B, linear fragment order
  __shared__ unsigned rowAbsU[GBM];         // per-row |acc| max (float bits)
  const int row0 = blockIdx.x*GBM;
  const int t = threadIdx.x;
  const int wave = t >> 6, lane = t & 63;
  const int wr = (wave >> 2)*64;
  const int colq = wave & 3;
  const int wc = colq*64;
  const int l15 = lane & 15, l4 = lane >> 4;

  if (t < GBM) rowAbsU[t] = 0;   // ordered before epilogue by loop barriers

  f32x4 acc[4][4] = {};

  for (int k0s = 0; k0s < KD/GBK; k0s++){
    const int k0 = k0s*GBK;
    {
      const unsigned short* gt = wcF + (size_t)k0s*16384;
      #pragma unroll
      for (int i = 0; i < 4; i++){
        int seg = wave*4 + i;
        glds16(gt + seg*512 + lane*8, BsL + seg*512);
      }
    }
    #pragma unroll
    for (int i = 0; i < 4; i++){
      int flat = t + 512*i;
      int r = flat >> 4, c4 = flat & 15;
      int gr = row0 + r;
      float4 v = {0.f,0.f,0.f,0.f};
      if (gr < n) v = *(const float4*)(feat + (size_t)gr*KD + k0 + c4*4);
      __hip_bfloat162 b01 = __float22bfloat162_rn(float2{v.x, v.y});
      __hip_bfloat162 b23 = __float22bfloat162_rn(float2{v.z, v.w});
      uint2 bw;
      bw.x = *(unsigned*)&b01; bw.y = *(unsigned*)&b23;
      *(uint2*)(&As[r][c4*4]) = bw;
    }
    __syncthreads();
    #pragma unroll
    for (int ks = 0; ks < 2; ks++){
      bf16x8 af[4], bfr[4];
      const int bbase = (colq*8 + ks*4)*512 + lane*8;
      #pragma unroll
      for (int nn = 0; nn < 4; nn++)
        bfr[nn] = *(const bf16x8*)(&BsL[bbase + nn*512]);
      #pragma unroll
      for (int m = 0; m < 4; m++)
        af[m] = *(const bf16x8*)(&As[wr + m*16 + l15][ks*32 + l4*8]);
      #pragma unroll
      for (int m = 0; m < 4; m++)
        #pragma unroll
        for (int nn = 0; nn < 4; nn++)
          acc[m][nn] = __builtin_amdgcn_mfma_f32_16x16x32_bf16(af[m], bfr[nn], acc[m][nn], 0, 0, 0);
    }
    __syncthreads();
  }
  // epilogue: apply norm, per-row absmax (LDS atomicMax), quantize to s8
  #pragma unroll
  for (int m = 0; m < 4; m++){
    #pragma unroll
    for (int r = 0; r < 4; r++){
      int rl = wr + m*16 + l4*4 + r;
      int row = row0 + rl;
      float ns = (row < n) ? norm_src[row] : 0.f;
      float am = 0.f;
      #pragma unroll
      for (int nn = 0; nn < 4; nn++){
        acc[m][nn][r] *= ns;
        am = fmaxf(am, fabsf(acc[m][nn][r]));
      }
      atomicMax(&rowAbsU[rl], __float_as_uint(am));
    }
  }
  __syncthreads();
  if (t < GBM){
    int row = row0 + t;
    if (row < n) scales[row] = __uint_as_float(rowAbsU[t]) * (1.0f/127.0f);
  }
  #pragma unroll
  for (int m = 0; m < 4; m++){
    #pragma unroll
    for (int r = 0; r < 4; r++){
      int rl = wr + m*16 + l4*4 + r;
      int row = row0 + rl;
      if (row < n){
        float mx = __uint_as_float(rowAbsU[rl]);
        float rec = (mx > 0.f) ? 127.0f/mx : 0.f;
        #pragma unroll
        for (int nn = 0; nn < 4; nn++){
          int col = wc + nn*16 + l15;
          h2[(size_t)row*OD + col] = (signed char)(int)rintf(acc[m][nn][r] * rec);
        }
      }
    }
  }
}

// ---- scan kernels ----
__global__ void k_scan2(const int* __restrict__ bsum, int* __restrict__ boff,
                        int nb, int* __restrict__ offsets, int n)
{
  int lane = threadIdx.x;  // 64 threads, 1 block
  int running = 0;
  for (int base = 0; base < nb; base += 64){
    int v = (base+lane < nb) ? bsum[base+lane] : 0;
    int x = v;
    #pragma unroll
    for (int d = 1; d < 64; d <<= 1){ int y = __shfl_up(x, d); if (lane >= d) x += y; }
    if (base+lane < nb) boff[base+lane] = running + x - v;
    running += __shfl(x, 63);
  }
  if (lane == 0) offsets[n] = running;   // = E
}

__global__ __launch_bounds__(256) void k_scan3(const int* __restrict__ cnt,
    const int* __restrict__ boff, int* __restrict__ offsets, int n)
{
  __shared__ int wsum[4], woff[4];
  int b = blockIdx.x, t = threadIdx.x, lane = t & 63, w = t >> 6;
  int base = b*1024 + t*4;
  int c[4]; int s = 0;
  #pragma unroll
  for (int i = 0; i < 4; i++){ c[i] = (base+i < n) ? cnt[base+i] : 0; s += c[i]; }
  int x = s;
  #pragma unroll
  for (int d = 1; d < 64; d <<= 1){ int y = __shfl_up(x, d); if (lane >= d) x += y; }
  if (lane == 63) wsum[w] = x;
  __syncthreads();
  if (t == 0){ int r = 0; for (int j = 0; j < 4; j++){ woff[j] = r; r += wsum[j]; } }
  __syncthreads();
  int excl = boff[b] + woff[w] + (x - s);
  #pragma unroll
  for (int i = 0; i < 4; i++){
    if (base+i < n) offsets[base+i] = excl;
    excl += c[i];
  }
}

// ---- scatter, ATOMIC-FREE (u8 metadata) ----
__global__ __launch_bounds__(256) void k_scatter(const int* __restrict__ src,
    const int* __restrict__ dst, const unsigned char* __restrict__ epos,
    const int* __restrict__ offsets, const unsigned char* __restrict__ cumB,
    int* __restrict__ esrc, int e, int n, int C)
{
  int i0 = (blockIdx.x*256 + threadIdx.x)*4;
  if (i0 + 3 < e){
    int b = i0 / C;
    const unsigned char* cb = cumB + (size_t)b*n;
    int4 a = *(const int4*)(src + i0);
    int4 d4 = *(const int4*)(dst + i0);
    unsigned pw = *(const unsigned*)(epos + i0);
    esrc[offsets[d4.x] + (int)cb[d4.x] + (int)( pw        & 0xFFu)] = a.x;
    esrc[offsets[d4.y] + (int)cb[d4.y] + (int)((pw >>  8) & 0xFFu)] = a.y;
    esrc[offsets[d4.z] + (int)cb[d4.z] + (int)((pw >> 16) & 0xFFu)] = a.z;
    esrc[offsets[d4.w] + (int)cb[d4.w] + (int)( pw >> 24        )] = a.w;
  } else {
    for (int i = i0; i < e; i++){
      int d = dst[i];
      int b = i / C;
      esrc[offsets[d] + (int)cumB[(size_t)b*n + d] + (int)epos[i]] = src[i];
    }
  }
}

// ---- aggregation over INT8 h2: one wave per dst node; 256B/edge (4 lines),
//      16 edges in flight; dequant via per-row scale fma ----
__global__ __launch_bounds__(256) void k_agg(const signed char* __restrict__ h2,
    const float* __restrict__ scales, const int* __restrict__ offsets,
    const int* __restrict__ esrc, const float* __restrict__ bias,
    float* __restrict__ out, int n)
{
  int node = (blockIdx.x*256 + threadIdx.x) >> 6;
  int lane = threadIdx.x & 63;
  if (node >= n) return;
  const int half = lane >> 5;        // which edge of the pair
  const int col8 = lane & 31;        // owns cols [col8*8, col8*8+8)
  int beg = offsets[node], end = offsets[node+1];

  float a0=0.f,a1=0.f,a2=0.f,a3=0.f,a4=0.f,a5=0.f,a6=0.f,a7=0.f;
  const signed char* hb = h2 + col8*8;

  #define ACCS(V, SC) { \
    unsigned wx = (V).x, wy = (V).y; \
    a0 += (SC)*(float)(int)(signed char)( wx        & 0xFFu); \
    a1 += (SC)*(float)(int)(signed char)((wx >>  8) & 0xFFu); \
    a2 += (SC)*(float)(int)(signed char)((wx >> 16) & 0xFFu); \
    a3 += (SC)*(float)(int)(signed char)( wx >> 24        ); \
    a4 += (SC)*(float)(int)(signed char)( wy        & 0xFFu); \
    a5 += (SC)*(float)(int)(signed char)((wy >>  8) & 0xFFu); \
    a6 += (SC)*(float)(int)(signed char)((wy >> 16) & 0xFFu); \
    a7 += (SC)*(float)(int)(signed char)( wy >> 24        ); }

  int i = beg;
  for (; i + 16 <= end; i += 16){
    int e0 = esrc[i      + half];
    int e1 = esrc[i +  2 + half];
    int e2 = esrc[i +  4 + half];
    int e3 = esrc[i +  6 + half];
    int e4 = esrc[i +  8 + half];
    int e5 = esrc[i + 10 + half];
    int e6 = esrc[i + 12 + half];
    int e7 = esrc[i + 14 + half];
    float s0 = scales[e0], s1 = scales[e1], s2 = scales[e2], s3 = scales[e3];
    float s4 = scales[e4], s5 = scales[e5], s6 = scales[e6], s7 = scales[e7];
    uint2 v0 = *(const uint2*)(hb + (size_t)e0*OD);
    uint2 v1 = *(const uint2*)(hb + (size_t)e1*OD);
    uint2 v2 = *(const uint2*)(hb + (size_t)e2*OD);
    uint2 v3 = *(const uint2*)(hb + (size_t)e3*OD);
    uint2 v4 = *(const uint2*)(hb + (size_t)e4*OD);
    uint2 v5 = *(const uint2*)(hb + (size_t)e5*OD);
    uint2 v6 = *(const uint2*)(hb + (size_t)e6*OD);
    uint2 v7 = *(const uint2*)(hb + (size_t)e7*OD);
    ACCS(v0, s0); ACCS(v1, s1); ACCS(v2, s2); ACCS(v3, s3);
    ACCS(v4, s4); ACCS(v5, s5); ACCS(v6, s6); ACCS(v7, s7);
  }
  for (; i + 2 <= end; i += 2){
    int e = esrc[i + half];
    float sc = scales[e];
    uint2 v = *(const uint2*)(hb + (size_t)e*OD);
    ACCS(v, sc);
  }
  if (i < end && half == 0){
    int e = esrc[i];
    float sc = scales[e];
    uint2 v = *(const uint2*)(hb + (size_t)e*OD);
    ACCS(v, sc);
  }
  #undef ACCS

  a0 += __shfl_xor(a0, 32); a1 += __shfl_xor(a1, 32);
  a2 += __shfl_xor(a2, 32); a3 += __shfl_xor(a3, 32);
  a4 += __shfl_xor(a4, 32); a5 += __shfl_xor(a5, 32);
  a6 += __shfl_xor(a6, 32); a7 += __shfl_xor(a7, 32);

  int d = end - beg; if (d < 1) d = 1;
  float nd = rsqrtf((float)d);
  int c0 = col8*8 + half*4;
  const float* bz = bias + c0;
  float4 o;
  if (half == 0){
    o.x = a0*nd + bz[0]; o.y = a1*nd + bz[1];
    o.z = a2*nd + bz[2]; o.w = a3*nd + bz[3];
  } else {
    o.x = a4*nd + bz[0]; o.y = a5*nd + bz[1];
    o.z = a6*nd + bz[2]; o.w = a7*nd + bz[3];
  }
  *(float4*)(out + (size_t)node*OD + c0) = o;
}

extern "C" void kernel_launch(void* const* d_in, const int* in_sizes, int n_in,
                              void* d_out, int out_size, void* d_ws, size_t ws_size,
                              hipStream_t stream)
{
  const float* feat     = (const float*)d_in[0];
  const float* weight   = (const float*)d_in[1];
  const float* bias     = (const float*)d_in[2];
  const float* st_param = (const float*)d_in[3];
  const int*   src      = (const int*)d_in[4];
  const int*   dst      = (const int*)d_in[5];
  const int N = in_sizes[0] / KD;
  const int E = in_sizes[4];

  char* w = (char*)d_ws;
  size_t off = 0;
  auto take = [&](size_t bytes) -> char* {
    char* p = w + off;
    off = (off + bytes + 255) & ~(size_t)255;
    return p;
  };
  unsigned char* cnt_out = (unsigned char*)take((size_t)BCH*N);
  unsigned char* cnt_in  = (unsigned char*)take((size_t)BCH*N);
  unsigned char* cumB    = (unsigned char*)take((size_t)BCH*N);
  unsigned char* epos    = (unsigned char*)take((size_t)E);
  int* indeg    = (int*)take((size_t)N*4);
  int* offsets  = (int*)take((size_t)(N+1)*4);
  int* bsum     = (int*)take(512*4);
  int* boff     = (int*)take(512*4);
  float* norm_src = (float*)take((size_t)N*4);
  float* scales   = (float*)take((size_t)N*4);
  unsigned short* wcF = (unsigned short*)take((size_t)KD*OD*2);
  int* esrc     = (int*)take((size_t)E*4);
  signed char* h2 = (signed char*)take((size_t)N*OD);
  (void)ws_size; (void)out_size; (void)n_in;

  float* out = (float*)d_out;

  int C = (((E + BCH - 1)/BCH) + 1023) & ~1023;
  int nparts = (N + RBIN - 1)/RBIN;   // = 2
  dim3 gho(BCH, nparts + 2);
  k_hist_out<<<gho, 256, 0, stream>>>(src, cnt_out, E, N, C, nparts, st_param, weight, wcF);
  dim3 ghi(BCH, nparts);
  k_hist_in <<<ghi, 256, 0, stream>>>(dst, cnt_in, epos, E, N, C);
  int nb = (N + 1023)/1024;
  k_red<<<nb, 256, 0, stream>>>(cnt_out, cnt_in, norm_src, indeg, cumB, bsum, N);
  k_scan2<<<1, 64, 0, stream>>>(bsum, boff, nb, offsets, N);
  k_scan3<<<nb, 256, 0, stream>>>(indeg, boff, offsets, N);
  int eb4 = (E + 1023)/1024;
  k_scatter<<<eb4, 256, 0, stream>>>(src, dst, epos, offsets, cumB, esrc, E, N, C);
  k_gemm_mfma<<<(N+GBM-1)/GBM, 512, 0, stream>>>(feat, wcF, norm_src, h2, scales, N);
  k_agg<<<(N+3)/4, 256, 0, stream>>>(h2, scales, offsets, esrc, bias, out, N);
}

// Round 16
// 324.721 us; speedup vs baseline: 1.3778x; 1.1120x over previous
//
#include <hip/hip_runtime.h>
#include <hip/hip_bf16.h>

#define T_ 4
#define FI_ 128
#define FO_ 64
#define KD 512     // T*FI
#define OD 256     // T*FO

#define RBIN 65536 // u8-packed LDS histogram bins per partition (64 KB)
#define RBW (RBIN/4)
#define BCH 128    // edge chunks (= rank-partial rows)

typedef __attribute__((ext_vector_type(8))) short bf16x8;
typedef __attribute__((ext_vector_type(4))) float f32x4;

static __device__ __forceinline__ float bf2f(unsigned short u){
  return __uint_as_float(((unsigned int)u) << 16);
}
static __device__ __forceinline__ unsigned short f2bf(float f){
  unsigned int u = __float_as_uint(f);
  u += 0x7FFFu + ((u >> 16) & 1u);
  return (unsigned short)(u >> 16);
}
// async global->LDS, 16B per lane; LDS dest = uniform base + lane*16 (linear)
static __device__ __forceinline__ void glds16(const void* g, void* l){
  __builtin_amdgcn_global_load_lds(
    (const __attribute__((address_space(1))) unsigned int*)g,
    (__attribute__((address_space(3))) unsigned int*)l, 16, 0, 0);
}

// ---- MERGED histogram kernel:
//      plane < nparts:            src (outdeg) histogram
//      nparts <= plane < 2nparts: dst (indeg) histogram + per-edge u8 rank
//      plane >= 2nparts:          wcF fragment-order build (2 planes)
//      All planes co-scheduled -> hist passes overlap (2 blocks/CU, 64KB LDS each) ----
__global__ __launch_bounds__(256) void k_hist(const int* __restrict__ src,
    const int* __restrict__ dst, unsigned char* __restrict__ cnt_out,
    unsigned char* __restrict__ cnt_in, unsigned char* __restrict__ epos,
    int e, int n, int C, int nparts,
    const float* __restrict__ st_param, const float* __restrict__ weight,
    unsigned short* __restrict__ wcF)
{
  const int plane = (int)blockIdx.y;
  if (plane >= 2*nparts){
    // ---- wcF build: 131072 elements over 2 planes x 128 blocks x 256 thr x 2 reps ----
    int base = (plane - 2*nparts)*(int)gridDim.x*256 + blockIdx.x*256 + threadIdx.x;
    #pragma unroll
    for (int rep = 0; rep < 2; rep++){
      int idx = base + rep*65536;
      if (idx < KD*OD){
        int c = idx >> 9, k = idx & 511;
        int s = k >> 7, f = k & 127, t = c >> 6, o = c & 63;
        float p0 = st_param[t*4+0], p1 = st_param[t*4+1], p2 = st_param[t*4+2], p3 = st_param[t*4+3];
        float m = fmaxf(fmaxf(p0,p1), fmaxf(p2,p3));
        float e0 = expf(p0-m), e1 = expf(p1-m), e2 = expf(p2-m), e3 = expf(p3-m);
        float sum = e0+e1+e2+e3;
        float sel = (s==0)?e0:((s==1)?e1:((s==2)?e2:e3));
        float v = (sel/sum) * weight[(t*FI_+f)*FO_ + o];
        int colq = c >> 6, cq = c & 63, nn = cq >> 4, l15 = cq & 15;
        int k0s = k >> 6, kk = k & 63, ks = kk >> 5, l4 = (kk >> 3) & 3, j = kk & 7;
        int lane = l4*16 + l15;
        size_t dest = ((((size_t)(k0s*4 + colq)*2 + ks)*4 + nn)*64 + lane)*8 + j;
        wcF[dest] = f2bf(v);
      }
    }
    return;
  }
  __shared__ unsigned h[RBW];
  for (int j = threadIdx.x; j < RBW; j += 256) h[j] = 0;
  __syncthreads();
  const bool isDst = plane >= nparts;
  const int part = isDst ? plane - nparts : plane;
  const int lo  = part * RBIN;
  const int beg = blockIdx.x * C;
  const int end = min(beg + C, e);
  const int* idxs = isDst ? dst : src;
  if (isDst){
    for (int i = beg + (int)threadIdx.x*4; i < end; i += 1024){
      if (i + 3 < end){
        int4 d4 = *(const int4*)(idxs + i);
        unsigned x0 = (unsigned)(d4.x - lo), x1 = (unsigned)(d4.y - lo);
        unsigned x2 = (unsigned)(d4.z - lo), x3 = (unsigned)(d4.w - lo);
        if (x0 < RBIN){ unsigned o = atomicAdd(&h[x0>>2], 1u << ((x0&3)*8));
                        epos[i  ] = (unsigned char)(o >> ((x0&3)*8)); }
        if (x1 < RBIN){ unsigned o = atomicAdd(&h[x1>>2], 1u << ((x1&3)*8));
                        epos[i+1] = (unsigned char)(o >> ((x1&3)*8)); }
        if (x2 < RBIN){ unsigned o = atomicAdd(&h[x2>>2], 1u << ((x2&3)*8));
                        epos[i+2] = (unsigned char)(o >> ((x2&3)*8)); }
        if (x3 < RBIN){ unsigned o = atomicAdd(&h[x3>>2], 1u << ((x3&3)*8));
                        epos[i+3] = (unsigned char)(o >> ((x3&3)*8)); }
      } else {
        for (int k = i; k < end; k++){
          unsigned x = (unsigned)(idxs[k] - lo);
          if (x < RBIN){ unsigned o = atomicAdd(&h[x>>2], 1u << ((x&3)*8));
                         epos[k] = (unsigned char)(o >> ((x&3)*8)); }
        }
      }
    }
  } else {
    for (int i = beg + (int)threadIdx.x*4; i < end; i += 1024){
      if (i + 3 < end){
        int4 s4 = *(const int4*)(idxs + i);
        unsigned x0 = (unsigned)(s4.x - lo), x1 = (unsigned)(s4.y - lo);
        unsigned x2 = (unsigned)(s4.z - lo), x3 = (unsigned)(s4.w - lo);
        if (x0 < RBIN) atomicAdd(&h[x0>>2], 1u << ((x0&3)*8));
        if (x1 < RBIN) atomicAdd(&h[x1>>2], 1u << ((x1&3)*8));
        if (x2 < RBIN) atomicAdd(&h[x2>>2], 1u << ((x2&3)*8));
        if (x3 < RBIN) atomicAdd(&h[x3>>2], 1u << ((x3&3)*8));
      } else {
        for (int k = i; k < end; k++){
          unsigned x = (unsigned)(idxs[k] - lo);
          if (x < RBIN) atomicAdd(&h[x>>2], 1u << ((x&3)*8));
        }
      }
    }
  }
  __syncthreads();
  const int hi = min(RBIN, n - lo);
  unsigned char* cnt = isDst ? cnt_in : cnt_out;
  unsigned* row = (unsigned*)(cnt + (size_t)blockIdx.x * n + lo);
  for (int j = threadIdx.x; j*4 < hi; j += 256) row[j] = h[j];
}

// ---- reduce chunk-partials: norm_src, indeg, cumB(u8), per-1024-block sums ----
__global__ __launch_bounds__(256) void k_red(const unsigned char* __restrict__ cnt_out,
    const unsigned char* __restrict__ cnt_in, float* __restrict__ norm_src,
    int* __restrict__ indeg, unsigned char* __restrict__ cumB,
    int* __restrict__ bsum, int n)
{
  __shared__ int wsums[4];
  int i0 = blockIdx.x*1024 + threadIdx.x*4;   // n % 4 == 0
  int o0=0,o1=0,o2=0,o3=0, c0=0,c1=0,c2=0,c3=0;
  if (i0 < n){
    #pragma unroll 8
    for (int b = 0; b < BCH; b++){
      unsigned wo = *(const unsigned*)(cnt_out + (size_t)b*n + i0);
      unsigned wi = *(const unsigned*)(cnt_in  + (size_t)b*n + i0);
      *(unsigned*)(cumB + (size_t)b*n + i0) =
          (unsigned)c0 | ((unsigned)c1<<8) | ((unsigned)c2<<16) | ((unsigned)c3<<24);
      o0 += wo & 0xFF; o1 += (wo>>8)&0xFF; o2 += (wo>>16)&0xFF; o3 += wo>>24;
      c0 += wi & 0xFF; c1 += (wi>>8)&0xFF; c2 += (wi>>16)&0xFF; c3 += wi>>24;
    }
    float4 ns;
    ns.x = rsqrtf((float)max(o0,1)); ns.y = rsqrtf((float)max(o1,1));
    ns.z = rsqrtf((float)max(o2,1)); ns.w = rsqrtf((float)max(o3,1));
    *(float4*)(norm_src + i0) = ns;
    int4 id; id.x=c0; id.y=c1; id.z=c2; id.w=c3;
    *(int4*)(indeg + i0) = id;
  }
  int s = c0+c1+c2+c3;
  #pragma unroll
  for (int d = 1; d < 64; d <<= 1) s += __shfl_xor(s, d);
  if ((threadIdx.x & 63) == 0) wsums[threadIdx.x>>6] = s;
  __syncthreads();
  if (threadIdx.x == 0) bsum[blockIdx.x] = wsums[0]+wsums[1]+wsums[2]+wsums[3];
}

// ---- MFMA bf16 GEMM, 128x256 tile, 8 waves; h2 emitted as BIASED u8 + per-row scale ----
#define GBM 128
#define GBK 64
#define ALD 72

__global__ __launch_bounds__(512) void k_gemm_mfma(
    const float* __restrict__ feat, const unsigned short* __restrict__ wcF,
    const float* __restrict__ norm_src, unsigned char* __restrict__ h2,
    float* __restrict__ scales, int n)
{
  __shared__ unsigned short As[GBM][ALD];   // 18432 B, padded
  __shared__ unsigned short BsL[16384];     // 32768 B, linear fragment order
  __shared__ unsigned rowAbsU[GBM];         // per-row |acc| max (float bits)
  const int row0 = blockIdx.x*GBM;
  const int t = threadIdx.x;
  const int wave = t >> 6, lane = t & 63;
  const int wr = (wave >> 2)*64;
  const int colq = wave & 3;
  const int wc = colq*64;
  const int l15 = lane & 15, l4 = lane >> 4;

  if (t < GBM) rowAbsU[t] = 0;   // ordered before epilogue by loop barriers

  f32x4 acc[4][4] = {};

  for (int k0s = 0; k0s < KD/GBK; k0s++){
    const int k0 = k0s*GBK;
    {
      const unsigned short* gt = wcF + (size_t)k0s*16384;
      #pragma unroll
      for (int i = 0; i < 4; i++){
        int seg = wave*4 + i;
        glds16(gt + seg*512 + lane*8, BsL + seg*512);
      }
    }
    #pragma unroll
    for (int i = 0; i < 4; i++){
      int flat = t + 512*i;
      int r = flat >> 4, c4 = flat & 15;
      int gr = row0 + r;
      float4 v = {0.f,0.f,0.f,0.f};
      if (gr < n) v = *(const float4*)(feat + (size_t)gr*KD + k0 + c4*4);
      __hip_bfloat162 b01 = __float22bfloat162_rn(float2{v.x, v.y});
      __hip_bfloat162 b23 = __float22bfloat162_rn(float2{v.z, v.w});
      uint2 bw;
      bw.x = *(unsigned*)&b01; bw.y = *(unsigned*)&b23;
      *(uint2*)(&As[r][c4*4]) = bw;
    }
    __syncthreads();
    #pragma unroll
    for (int ks = 0; ks < 2; ks++){
      bf16x8 af[4], bfr[4];
      const int bbase = (colq*8 + ks*4)*512 + lane*8;
      #pragma unroll
      for (int nn = 0; nn < 4; nn++)
        bfr[nn] = *(const bf16x8*)(&BsL[bbase + nn*512]);
      #pragma unroll
      for (int m = 0; m < 4; m++)
        af[m] = *(const bf16x8*)(&As[wr + m*16 + l15][ks*32 + l4*8]);
      #pragma unroll
      for (int m = 0; m < 4; m++)
        #pragma unroll
        for (int nn = 0; nn < 4; nn++)
          acc[m][nn] = __builtin_amdgcn_mfma_f32_16x16x32_bf16(af[m], bfr[nn], acc[m][nn], 0, 0, 0);
    }
    __syncthreads();
  }
  // epilogue: apply norm, per-row absmax (LDS atomicMax), quantize to biased u8
  #pragma unroll
  for (int m = 0; m < 4; m++){
    #pragma unroll
    for (int r = 0; r < 4; r++){
      int rl = wr + m*16 + l4*4 + r;
      int row = row0 + rl;
      float ns = (row < n) ? norm_src[row] : 0.f;
      float am = 0.f;
      #pragma unroll
      for (int nn = 0; nn < 4; nn++){
        acc[m][nn][r] *= ns;
        am = fmaxf(am, fabsf(acc[m][nn][r]));
      }
      atomicMax(&rowAbsU[rl], __float_as_uint(am));
    }
  }
  __syncthreads();
  if (t < GBM){
    int row = row0 + t;
    if (row < n) scales[row] = __uint_as_float(rowAbsU[t]) * (1.0f/127.0f);
  }
  #pragma unroll
  for (int m = 0; m < 4; m++){
    #pragma unroll
    for (int r = 0; r < 4; r++){
      int rl = wr + m*16 + l4*4 + r;
      int row = row0 + rl;
      if (row < n){
        float mx = __uint_as_float(rowAbsU[rl]);
        float rec = (mx > 0.f) ? 127.0f/mx : 0.f;
        #pragma unroll
        for (int nn = 0; nn < 4; nn++){
          int col = wc + nn*16 + l15;
          h2[(size_t)row*OD + col] =
              (unsigned char)((int)rintf(acc[m][nn][r] * rec) + 128);
        }
      }
    }
  }
}

// ---- scan kernels ----
__global__ void k_scan2(const int* __restrict__ bsum, int* __restrict__ boff,
                        int nb, int* __restrict__ offsets, int n)
{
  int lane = threadIdx.x;  // 64 threads, 1 block
  int running = 0;
  for (int base = 0; base < nb; base += 64){
    int v = (base+lane < nb) ? bsum[base+lane] : 0;
    int x = v;
    #pragma unroll
    for (int d = 1; d < 64; d <<= 1){ int y = __shfl_up(x, d); if (lane >= d) x += y; }
    if (base+lane < nb) boff[base+lane] = running + x - v;
    running += __shfl(x, 63);
  }
  if (lane == 0) offsets[n] = running;   // = E
}

__global__ __launch_bounds__(256) void k_scan3(const int* __restrict__ cnt,
    const int* __restrict__ boff, int* __restrict__ offsets, int n)
{
  __shared__ int wsum[4], woff[4];
  int b = blockIdx.x, t = threadIdx.x, lane = t & 63, w = t >> 6;
  int base = b*1024 + t*4;
  int c[4]; int s = 0;
  #pragma unroll
  for (int i = 0; i < 4; i++){ c[i] = (base+i < n) ? cnt[base+i] : 0; s += c[i]; }
  int x = s;
  #pragma unroll
  for (int d = 1; d < 64; d <<= 1){ int y = __shfl_up(x, d); if (lane >= d) x += y; }
  if (lane == 63) wsum[w] = x;
  __syncthreads();
  if (t == 0){ int r = 0; for (int j = 0; j < 4; j++){ woff[j] = r; r += wsum[j]; } }
  __syncthreads();
  int excl = boff[b] + woff[w] + (x - s);
  #pragma unroll
  for (int i = 0; i < 4; i++){
    if (base+i < n) offsets[base+i] = excl;
    excl += c[i];
  }
}

// ---- scatter, ATOMIC-FREE (u8 metadata) ----
__global__ __launch_bounds__(256) void k_scatter(const int* __restrict__ src,
    const int* __restrict__ dst, const unsigned char* __restrict__ epos,
    const int* __restrict__ offsets, const unsigned char* __restrict__ cumB,
    int* __restrict__ esrc, int e, int n, int C)
{
  int i0 = (blockIdx.x*256 + threadIdx.x)*4;
  if (i0 + 3 < e){
    int b = i0 / C;
    const unsigned char* cb = cumB + (size_t)b*n;
    int4 a = *(const int4*)(src + i0);
    int4 d4 = *(const int4*)(dst + i0);
    unsigned pw = *(const unsigned*)(epos + i0);
    esrc[offsets[d4.x] + (int)cb[d4.x] + (int)( pw        & 0xFFu)] = a.x;
    esrc[offsets[d4.y] + (int)cb[d4.y] + (int)((pw >>  8) & 0xFFu)] = a.y;
    esrc[offsets[d4.z] + (int)cb[d4.z] + (int)((pw >> 16) & 0xFFu)] = a.z;
    esrc[offsets[d4.w] + (int)cb[d4.w] + (int)( pw >> 24        )] = a.w;
  } else {
    for (int i = i0; i < e; i++){
      int d = dst[i];
      int b = i / C;
      esrc[offsets[d] + (int)cumB[(size_t)b*n + d] + (int)epos[i]] = src[i];
    }
  }
}

// ---- aggregation over BIASED u8 h2: dequant (u-128)*sc via cvt_f32_ubyte + deferred
//      bias correction (a_j -= 128*Σsc). 2 ops/element instead of 3. ----
__global__ __launch_bounds__(256) void k_agg(const unsigned char* __restrict__ h2,
    const float* __restrict__ scales, const int* __restrict__ offsets,
    const int* __restrict__ esrc, const float* __restrict__ bias,
    float* __restrict__ out, int n)
{
  int node = (blockIdx.x*256 + threadIdx.x) >> 6;
  int lane = threadIdx.x & 63;
  if (node >= n) return;
  const int half = lane >> 5;        // which edge of the pair
  const int col8 = lane & 31;        // owns cols [col8*8, col8*8+8)
  int beg = offsets[node], end = offsets[node+1];

  float a0=0.f,a1=0.f,a2=0.f,a3=0.f,a4=0.f,a5=0.f,a6=0.f,a7=0.f;
  float ssum = 0.f;
  const unsigned char* hb = h2 + col8*8;

  #define ACCU(V, SC) { \
    unsigned wx = (V).x, wy = (V).y; \
    a0 += (SC)*(float)( wx        & 0xFFu); \
    a1 += (SC)*(float)((wx >>  8) & 0xFFu); \
    a2 += (SC)*(float)((wx >> 16) & 0xFFu); \
    a3 += (SC)*(float)( wx >> 24        ); \
    a4 += (SC)*(float)( wy        & 0xFFu); \
    a5 += (SC)*(float)((wy >>  8) & 0xFFu); \
    a6 += (SC)*(float)((wy >> 16) & 0xFFu); \
    a7 += (SC)*(float)( wy >> 24        ); \
    ssum += (SC); }

  int i = beg;
  for (; i + 16 <= end; i += 16){
    int e0 = esrc[i      + half];
    int e1 = esrc[i +  2 + half];
    int e2 = esrc[i +  4 + half];
    int e3 = esrc[i +  6 + half];
    int e4 = esrc[i +  8 + half];
    int e5 = esrc[i + 10 + half];
    int e6 = esrc[i + 12 + half];
    int e7 = esrc[i + 14 + half];
    float s0 = scales[e0], s1 = scales[e1], s2 = scales[e2], s3 = scales[e3];
    float s4 = scales[e4], s5 = scales[e5], s6 = scales[e6], s7 = scales[e7];
    uint2 v0 = *(const uint2*)(hb + (size_t)e0*OD);
    uint2 v1 = *(const uint2*)(hb + (size_t)e1*OD);
    uint2 v2 = *(const uint2*)(hb + (size_t)e2*OD);
    uint2 v3 = *(const uint2*)(hb + (size_t)e3*OD);
    uint2 v4 = *(const uint2*)(hb + (size_t)e4*OD);
    uint2 v5 = *(const uint2*)(hb + (size_t)e5*OD);
    uint2 v6 = *(const uint2*)(hb + (size_t)e6*OD);
    uint2 v7 = *(const uint2*)(hb + (size_t)e7*OD);
    ACCU(v0, s0); ACCU(v1, s1); ACCU(v2, s2); ACCU(v3, s3);
    ACCU(v4, s4); ACCU(v5, s5); ACCU(v6, s6); ACCU(v7, s7);
  }
  for (; i + 2 <= end; i += 2){
    int e = esrc[i + half];
    float sc = scales[e];
    uint2 v = *(const uint2*)(hb + (size_t)e*OD);
    ACCU(v, sc);
  }
  if (i < end && half == 0){
    int e = esrc[i];
    float sc = scales[e];
    uint2 v = *(const uint2*)(hb + (size_t)e*OD);
    ACCU(v, sc);
  }
  #undef ACCU

  a0 += __shfl_xor(a0, 32); a1 += __shfl_xor(a1, 32);
  a2 += __shfl_xor(a2, 32); a3 += __shfl_xor(a3, 32);
  a4 += __shfl_xor(a4, 32); a5 += __shfl_xor(a5, 32);
  a6 += __shfl_xor(a6, 32); a7 += __shfl_xor(a7, 32);
  ssum += __shfl_xor(ssum, 32);

  float corr = 128.0f * ssum;
  a0 -= corr; a1 -= corr; a2 -= corr; a3 -= corr;
  a4 -= corr; a5 -= corr; a6 -= corr; a7 -= corr;

  int d = end - beg; if (d < 1) d = 1;
  float nd = rsqrtf((float)d);
  int c0 = col8*8 + half*4;
  const float* bz = bias + c0;
  float4 o;
  if (half == 0){
    o.x = a0*nd + bz[0]; o.y = a1*nd + bz[1];
    o.z = a2*nd + bz[2]; o.w = a3*nd + bz[3];
  } else {
    o.x = a4*nd + bz[0]; o.y = a5*nd + bz[1];
    o.z = a6*nd + bz[2]; o.w = a7*nd + bz[3];
  }
  *(float4*)(out + (size_t)node*OD + c0) = o;
}

extern "C" void kernel_launch(void* const* d_in, const int* in_sizes, int n_in,
                              void* d_out, int out_size, void* d_ws, size_t ws_size,
                              hipStream_t stream)
{
  const float* feat     = (const float*)d_in[0];
  const float* weight   = (const float*)d_in[1];
  const float* bias     = (const float*)d_in[2];
  const float* st_param = (const float*)d_in[3];
  const int*   src      = (const int*)d_in[4];
  const int*   dst      = (const int*)d_in[5];
  const int N = in_sizes[0] / KD;
  const int E = in_sizes[4];

  char* w = (char*)d_ws;
  size_t off = 0;
  auto take = [&](size_t bytes) -> char* {
    char* p = w + off;
    off = (off + bytes + 255) & ~(size_t)255;
    return p;
  };
  unsigned char* cnt_out = (unsigned char*)take((size_t)BCH*N);
  unsigned char* cnt_in  = (unsigned char*)take((size_t)BCH*N);
  unsigned char* cumB    = (unsigned char*)take((size_t)BCH*N);
  unsigned char* epos    = (unsigned char*)take((size_t)E);
  int* indeg    = (int*)take((size_t)N*4);
  int* offsets  = (int*)take((size_t)(N+1)*4);
  int* bsum     = (int*)take(512*4);
  int* boff     = (int*)take(512*4);
  float* norm_src = (float*)take((size_t)N*4);
  float* scales   = (float*)take((size_t)N*4);
  unsigned short* wcF = (unsigned short*)take((size_t)KD*OD*2);
  int* esrc     = (int*)take((size_t)E*4);
  unsigned char* h2 = (unsigned char*)take((size_t)N*OD);
  (void)ws_size; (void)out_size; (void)n_in;

  float* out = (float*)d_out;

  int C = (((E + BCH - 1)/BCH) + 1023) & ~1023;
  int nparts = (N + RBIN - 1)/RBIN;   // = 2
  // merged grid: nparts src-hist + nparts dst-hist + 2 wc planes
  dim3 gh(BCH, 2*nparts + 2);
  k_hist<<<gh, 256, 0, stream>>>(src, dst, cnt_out, cnt_in, epos, E, N, C,
                                 nparts, st_param, weight, wcF);
  int nb = (N + 1023)/1024;
  k_red<<<nb, 256, 0, stream>>>(cnt_out, cnt_in, norm_src, indeg, cumB, bsum, N);
  k_scan2<<<1, 64, 0, stream>>>(bsum, boff, nb, offsets, N);
  k_scan3<<<nb, 256, 0, stream>>>(indeg, boff, offsets, N);
  int eb4 = (E + 1023)/1024;
  k_scatter<<<eb4, 256, 0, stream>>>(src, dst, epos, offsets, cumB, esrc, E, N, C);
  k_gemm_mfma<<<(N+GBM-1)/GBM, 512, 0, stream>>>(feat, wcF, norm_src, h2, scales, N);
  k_agg<<<(N+3)/4, 256, 0, stream>>>(h2, scales, offsets, esrc, bias, out, N);
}